// Round 1
// baseline (1536.797 us; speedup 1.0000x reference)
//
#include <hip/hip_runtime.h>
#include <math.h>

// Problem constants
#define VV 32000   // vocab
#define SS 512     // states
#define BB 64      // batch
#define TT 256     // maxlen
#define NS 128     // column groups of 4 (512/4)
#define NPART 500  // colsum partials (250 blocks x 2 row-halves)
#define NCB 128    // blocks per chain (grid 256 = 2 chains x 128)
#define WSLOT (BB * SS)  // floats per w time-slot (32768)

// ---------------- setup kernels ----------------

__global__ void k_zero(float* __restrict__ out, float* __restrict__ colsum,
                       unsigned* __restrict__ barcnt) {
  const int t = threadIdx.x;  // 512
  if (t == 0) { out[0] = 0.f; barcnt[0] = 0u; barcnt[1] = 0u; }
  colsum[t] = 0.f;
}

// Column sums of exp(iw) over vocab rows. Inputs are U(-0.5,0.5) so exp() is
// in (0.6, 1.65) — no max-subtraction needed (sum ~3.4e4, f32-safe).
__global__ void k_colpart(const float* __restrict__ iw, float* __restrict__ psum) {
  const int blk = blockIdx.x;        // 250
  const int tid = threadIdx.x;       // 256
  const int cg = tid & 127;          // float4 column group
  const int rh = tid >> 7;           // row half
  const int r0 = blk * 128 + rh * 64;
  const float4* iw4 = (const float4*)iw;   // [32000][128] float4
  float4 s = make_float4(0.f, 0.f, 0.f, 0.f);
  #pragma unroll 4
  for (int r = 0; r < 64; ++r) {
    float4 x = iw4[(size_t)(r0 + r) * 128 + cg];
    s.x += __expf(x.x); s.y += __expf(x.y); s.z += __expf(x.z); s.w += __expf(x.w);
  }
  ((float4*)psum)[(size_t)(blk * 2 + rh) * 128 + cg] = s;
}

// 25 blocks x 512 thr: block p sums partial rows [20p, 20p+20) -> atomicAdd.
__global__ void k_colreduce(const float* __restrict__ psum, float* __restrict__ colsum) {
  const int c = threadIdx.x;         // 512
  const int p0 = blockIdx.x * 20;
  float s = 0.f;
  #pragma unroll 5
  for (int p = 0; p < 20; ++p) s += psum[(size_t)(p0 + p) * SS + c];
  atomicAdd(&colsum[c], s);
}

__global__ void k_lse(const float* __restrict__ colsum, float* __restrict__ colLSE) {
  colLSE[threadIdx.x] = __logf(colsum[threadIdx.x]);
}

// sb = softmax(begin)
__global__ void k_begin(const float* __restrict__ begin, float* __restrict__ sb) {
  __shared__ float red[8];
  const int tid = threadIdx.x;  // 512
  float x = begin[tid];
  float m = x;
  #pragma unroll
  for (int o = 32; o; o >>= 1) m = fmaxf(m, __shfl_xor(m, o));
  if ((tid & 63) == 0) red[tid >> 6] = m;
  __syncthreads();
  float bm = red[0];
  for (int i = 1; i < 8; ++i) bm = fmaxf(bm, red[i]);
  __syncthreads();
  float e = __expf(x - bm);
  float s = e;
  #pragma unroll
  for (int o = 32; o; o >>= 1) s += __shfl_xor(s, o);
  if ((tid & 63) == 0) red[tid >> 6] = s;
  __syncthreads();
  float tot = 0.f;
  for (int i = 0; i < 8; ++i) tot += red[i];
  sb[tid] = e / tot;
}

// P[i][j] = softmax(transition[i,:])[j] (row-major), q0vec[i] = sum_j P[i,j]*sb[j]
__global__ void k_transP(const float* __restrict__ trans, const float* __restrict__ sb,
                         float* __restrict__ P, float* __restrict__ q0vec) {
  const int i = blockIdx.x;     // 512 rows
  const int lane = threadIdx.x; // 64
  const float* rp = trans + (size_t)i * SS;
  float xs[8];
  float m = -1e30f;
  #pragma unroll
  for (int cc = 0; cc < 8; ++cc) { xs[cc] = rp[cc * 64 + lane]; m = fmaxf(m, xs[cc]); }
  #pragma unroll
  for (int o = 32; o; o >>= 1) m = fmaxf(m, __shfl_xor(m, o));
  float s = 0.f;
  #pragma unroll
  for (int cc = 0; cc < 8; ++cc) s += __expf(xs[cc] - m);
  #pragma unroll
  for (int o = 32; o; o >>= 1) s += __shfl_xor(s, o);
  const float lse = m + __logf(s);
  float qa = 0.f;
  #pragma unroll
  for (int cc = 0; cc < 8; ++cc) {
    float p = __expf(xs[cc] - lse);
    P[(size_t)i * SS + cc * 64 + lane] = p;
    qa += p * sb[cc * 64 + lane];
  }
  #pragma unroll
  for (int o = 32; o; o >>= 1) qa += __shfl_xor(qa, o);
  if (lane == 0) q0vec[i] = qa;
}

// ---------------- persistent superstep kernel ----------------
// Replaces the 129 k_step launches. 256 blocks x 256 thr, cooperative launch.
// chain c = blk&1, column group g = blk>>1 (4 states). Wave h = j-quarter.
//
// w ring is WRITE-ONCE: slot index = timestep t (255 slots). No address is
// ever rewritten, so no XCD-L2 can hold a stale w line -> plain cached loads
// are coherent. Visibility: writer's barrier-arrive uses RELEASE (agent) =>
// s_waitcnt + buffer_wbl2 pushes w stores to L3 before the count ticks.
// Per-chain barrier: monotonic counter, 128 arrivals per superstep.
__global__ __launch_bounds__(256) void k_persist(
    const float* __restrict__ P, const float* __restrict__ q0vec,
    const float* __restrict__ iw, const float* __restrict__ colLSE,
    const int* __restrict__ sent, float* __restrict__ wring,
    float* __restrict__ dotpart, unsigned* __restrict__ barcnt) {
  const int c = blockIdx.x & 1;
  const int g = blockIdx.x >> 1;       // 0..127
  const int lane = threadIdx.x & 63;   // batch b
  const int h = __builtin_amdgcn_readfirstlane(threadIdx.x >> 6); // j-quarter
  const int i0 = g << 2;
  const int kmax = c ? 127 : 128;

  // loop-invariant hoists
  const float4 cl = *(const float4*)(colLSE + i0);
  const float4* const P0 = (const float4*)(P + (size_t)(i0 + 0) * SS) + h * 32;
  const float4* const P1 = (const float4*)(P + (size_t)(i0 + 1) * SS) + h * 32;
  const float4* const P2 = (const float4*)(P + (size_t)(i0 + 2) * SS) + h * 32;
  const float4* const P3 = (const float4*)(P + (size_t)(i0 + 3) * SS) + h * 32;

  __shared__ float4 red[4][64];

  for (int k = 0; k <= kmax; ++k) {
    const int t0 = 2 * k;
    const int tw = t0 + c;
    const int td = tw - 1;
    const bool doW = (h == 0) && (tw <= 254);
    const bool doD = (h == 1) && (td >= 0);

    // Issue the scattered iw gathers BEFORE the barrier: independent of w,
    // their L3 latency hides under the spin/arrival skew.
    float4 ivW = make_float4(0.f, 0.f, 0.f, 0.f);
    float4 ivD = make_float4(0.f, 0.f, 0.f, 0.f);
    if (doW) {
      const int row = sent[lane * TT + tw];
      ivW = *(const float4*)(iw + (size_t)row * SS + i0);
    }
    if (doD) {
      const int row = sent[lane * TT + td];
      ivD = *(const float4*)(iw + (size_t)row * SS + i0);
    }

    if (k > 0) {
      __syncthreads();  // all waves done with previous superstep (red reads + w stores issued)
      if (threadIdx.x == 0) {
        // RELEASE: waits wave0's w stores (vmcnt) + buffer_wbl2 -> w visible in L3
        __hip_atomic_fetch_add(barcnt + c, 1u, __ATOMIC_RELEASE, __HIP_MEMORY_SCOPE_AGENT);
        const unsigned tgt = (unsigned)(NCB * k);
        while (__hip_atomic_load(barcnt + c, __ATOMIC_RELAXED, __HIP_MEMORY_SCOPE_AGENT) < tgt)
          __builtin_amdgcn_s_sleep(2);
      }
      __syncthreads();
      asm volatile("" ::: "memory");  // compiler fence; no HW inv needed (write-once ring)
    }

    float a0 = 0.f, a1 = 0.f, a2 = 0.f, a3 = 0.f;
    if (t0 == 0) {
      if (h == 0) {
        a0 = q0vec[i0 + 0]; a1 = q0vec[i0 + 1];
        a2 = q0vec[i0 + 2]; a3 = q0vec[i0 + 3];
      }
    } else {
      const float4* wv = (const float4*)(wring + (size_t)(tw - 2) * WSLOT) + (size_t)h * 32 * 64;
      #pragma unroll 4
      for (int j4 = 0; j4 < 32; ++j4) {
        const float4 w4 = wv[j4 * 64 + lane];
        const float4 p0 = P0[j4];
        const float4 p1 = P1[j4];
        const float4 p2 = P2[j4];
        const float4 p3 = P3[j4];
        a0 += w4.x * p0.x + w4.y * p0.y + w4.z * p0.z + w4.w * p0.w;
        a1 += w4.x * p1.x + w4.y * p1.y + w4.z * p1.z + w4.w * p1.w;
        a2 += w4.x * p2.x + w4.y * p2.y + w4.z * p2.z + w4.w * p2.w;
        a3 += w4.x * p3.x + w4.y * p3.y + w4.z * p3.z + w4.w * p3.w;
      }
    }

    red[h][lane] = make_float4(a0, a1, a2, a3);
    __syncthreads();

    if (h < 2) {
      const float4 r0 = red[0][lane], r1 = red[1][lane];
      const float4 r2 = red[2][lane], r3 = red[3][lane];
      const float s0 = (r0.x + r1.x) + (r2.x + r3.x);
      const float s1 = (r0.y + r1.y) + (r2.y + r3.y);
      const float s2 = (r0.z + r1.z) + (r2.z + r3.z);
      const float s3 = (r0.w + r1.w) + (r2.w + r3.w);

      if (doW) {
        float w0 = s0 * __expf(ivW.x - cl.x);
        float w1 = s1 * __expf(ivW.y - cl.y);
        float w2 = s2 * __expf(ivW.z - cl.z);
        float w3 = s3 * __expf(ivW.w - cl.w);
        float c0 = w0, c1 = w1, c2 = w2, c3 = w3;
        #pragma unroll
        for (int o = 32; o; o >>= 1) {
          c0 += __shfl_xor(c0, o);
          c1 += __shfl_xor(c1, o);
          c2 += __shfl_xor(c2, o);
          c3 += __shfl_xor(c3, o);
        }
        float4 wo;
        wo.x = w0 / c0; wo.y = w1 / c1; wo.z = w2 / c2; wo.w = w3 / c3;
        ((float4*)(wring + (size_t)tw * WSLOT))[g * 64 + lane] = wo;
      }

      if (doD) {
        const float dp = s0 * __expf(ivD.x - cl.x)
                       + s1 * __expf(ivD.y - cl.y)
                       + s2 * __expf(ivD.z - cl.z)
                       + s3 * __expf(ivD.w - cl.w);
        dotpart[((size_t)td * NS + g) * BB + lane] = dp;
      }
    }
  }
}

// ---------------- final reduction ----------------
__global__ void k_final(const float* __restrict__ dotpart, const float* __restrict__ masks,
                        float* __restrict__ out) {
  const int t = blockIdx.x;    // 256
  const int tid = threadIdx.x; // 256
  const int b = tid & 63, g = tid >> 6;
  float sum = 0.f;
  for (int s = g; s < NS; s += 4) sum += dotpart[((size_t)t * NS + s) * BB + b];
  __shared__ float red[4][64];
  red[g][b] = sum;
  __syncthreads();
  if (g == 0) {
    float tot = (red[0][b] + red[1][b]) + (red[2][b] + red[3][b]);
    float v = __logf(tot) * masks[b * TT + t];
    #pragma unroll
    for (int o = 32; o; o >>= 1) v += __shfl_xor(v, o);
    if (b == 0) atomicAdd(out, v);
  }
}

extern "C" void kernel_launch(void* const* d_in, const int* in_sizes, int n_in,
                              void* d_out, int out_size, void* d_ws, size_t ws_size,
                              hipStream_t stream) {
  const int* sent = (const int*)d_in[0];     // [64][256] int32
  const float* masks = (const float*)d_in[1];// [64][256]
  const float* iw = (const float*)d_in[2];   // [32000][512]
  const float* trans = (const float*)d_in[3];// [512][512]
  const float* begin = (const float*)d_in[4];// [512]
  float* out = (float*)d_out;
  float* ws = (float*)d_ws;

  // workspace carve (floats)
  float* P = ws;                            // 262144
  float* colLSE = P + 262144;               // 512
  float* psum = colLSE + 512;               // 256000
  float* colsum = psum + 256000;            // 512
  float* sb = colsum + 512;                 // 512
  float* q0vec = sb + 512;                  // 512
  float* dotpart = q0vec + 512;             // 256*128*64 = 2097152
  unsigned* barcnt = (unsigned*)(dotpart + 2097152); // 2 used, 64 reserved
  float* wring = (float*)barcnt + 64;       // 255 * 32768 = 8355840 (~33.4 MB)
  // total ~44 MB (workspace poison fill shows ~256 MB available)

  k_zero<<<1, 512, 0, stream>>>(out, colsum, barcnt);
  k_colpart<<<250, 256, 0, stream>>>(iw, psum);
  k_colreduce<<<25, 512, 0, stream>>>(psum, colsum);
  k_lse<<<1, 512, 0, stream>>>(colsum, colLSE);
  k_begin<<<1, 512, 0, stream>>>(begin, sb);
  k_transP<<<512, 64, 0, stream>>>(trans, sb, P, q0vec);

  {
    const float* Pp = P;
    const float* q0p = q0vec;
    const float* iwp = iw;
    const float* clp = colLSE;
    const int* sentp = sent;
    float* wrp = wring;
    float* dpp = dotpart;
    unsigned* bcp = barcnt;
    void* args[] = {&Pp, &q0p, &iwp, &clp, &sentp, &wrp, &dpp, &bcp};
    hipLaunchCooperativeKernel((const void*)k_persist, dim3(256), dim3(256),
                               args, 0, stream);
  }

  k_final<<<TT, 256, 0, stream>>>(dotpart, masks, out);
}

// Round 3
// 786.891 us; speedup vs baseline: 1.9530x; 1.9530x over previous
//
#include <hip/hip_runtime.h>
#include <math.h>

// Problem constants
#define VV 32000   // vocab
#define SS 512     // states
#define BB 64      // batch
#define TT 256     // maxlen
#define NS 128     // column groups of 4 (512/4)
#define NPART 500  // colsum partials (250 blocks x 2 row-halves)
#define NCB 128    // blocks per chain (grid 256 = 2 chains x 128)
#define WSLOT (BB * SS)  // floats per w time-slot (32768)

// ---------------- setup kernels ----------------

__global__ void k_zero(float* __restrict__ out, float* __restrict__ colsum,
                       unsigned* __restrict__ flags) {
  const int t = threadIdx.x;  // 512
  if (t == 0) out[0] = 0.f;
  if (t < 256) flags[t] = 0u;
  colsum[t] = 0.f;
}

// Column sums of exp(iw) over vocab rows. Inputs are U(-0.5,0.5) so exp() is
// in (0.6, 1.65) — no max-subtraction needed (sum ~3.4e4, f32-safe).
__global__ void k_colpart(const float* __restrict__ iw, float* __restrict__ psum) {
  const int blk = blockIdx.x;        // 250
  const int tid = threadIdx.x;       // 256
  const int cg = tid & 127;          // float4 column group
  const int rh = tid >> 7;           // row half
  const int r0 = blk * 128 + rh * 64;
  const float4* iw4 = (const float4*)iw;   // [32000][128] float4
  float4 s = make_float4(0.f, 0.f, 0.f, 0.f);
  #pragma unroll 4
  for (int r = 0; r < 64; ++r) {
    float4 x = iw4[(size_t)(r0 + r) * 128 + cg];
    s.x += __expf(x.x); s.y += __expf(x.y); s.z += __expf(x.z); s.w += __expf(x.w);
  }
  ((float4*)psum)[(size_t)(blk * 2 + rh) * 128 + cg] = s;
}

// 25 blocks x 512 thr: block p sums partial rows [20p, 20p+20) -> atomicAdd.
__global__ void k_colreduce(const float* __restrict__ psum, float* __restrict__ colsum) {
  const int c = threadIdx.x;         // 512
  const int p0 = blockIdx.x * 20;
  float s = 0.f;
  #pragma unroll 5
  for (int p = 0; p < 20; ++p) s += psum[(size_t)(p0 + p) * SS + c];
  atomicAdd(&colsum[c], s);
}

__global__ void k_lse(const float* __restrict__ colsum, float* __restrict__ colLSE) {
  colLSE[threadIdx.x] = __logf(colsum[threadIdx.x]);
}

// sb = softmax(begin)
__global__ void k_begin(const float* __restrict__ begin, float* __restrict__ sb) {
  __shared__ float red[8];
  const int tid = threadIdx.x;  // 512
  float x = begin[tid];
  float m = x;
  #pragma unroll
  for (int o = 32; o; o >>= 1) m = fmaxf(m, __shfl_xor(m, o));
  if ((tid & 63) == 0) red[tid >> 6] = m;
  __syncthreads();
  float bm = red[0];
  for (int i = 1; i < 8; ++i) bm = fmaxf(bm, red[i]);
  __syncthreads();
  float e = __expf(x - bm);
  float s = e;
  #pragma unroll
  for (int o = 32; o; o >>= 1) s += __shfl_xor(s, o);
  if ((tid & 63) == 0) red[tid >> 6] = s;
  __syncthreads();
  float tot = 0.f;
  for (int i = 0; i < 8; ++i) tot += red[i];
  sb[tid] = e / tot;
}

// P[i][j] = softmax(transition[i,:])[j] (row-major), q0vec[i] = sum_j P[i,j]*sb[j]
__global__ void k_transP(const float* __restrict__ trans, const float* __restrict__ sb,
                         float* __restrict__ P, float* __restrict__ q0vec) {
  const int i = blockIdx.x;     // 512 rows
  const int lane = threadIdx.x; // 64
  const float* rp = trans + (size_t)i * SS;
  float xs[8];
  float m = -1e30f;
  #pragma unroll
  for (int cc = 0; cc < 8; ++cc) { xs[cc] = rp[cc * 64 + lane]; m = fmaxf(m, xs[cc]); }
  #pragma unroll
  for (int o = 32; o; o >>= 1) m = fmaxf(m, __shfl_xor(m, o));
  float s = 0.f;
  #pragma unroll
  for (int cc = 0; cc < 8; ++cc) s += __expf(xs[cc] - m);
  #pragma unroll
  for (int o = 32; o; o >>= 1) s += __shfl_xor(s, o);
  const float lse = m + __logf(s);
  float qa = 0.f;
  #pragma unroll
  for (int cc = 0; cc < 8; ++cc) {
    float p = __expf(xs[cc] - lse);
    P[(size_t)i * SS + cc * 64 + lane] = p;
    qa += p * sb[cc * 64 + lane];
  }
  #pragma unroll
  for (int o = 32; o; o >>= 1) qa += __shfl_xor(qa, o);
  if (lane == 0) q0vec[i] = qa;
}

// ---------------- persistent superstep kernel ----------------
// 256 blocks x 256 thr, cooperative. chain c = blk&1, col group g = blk>>1.
// Wave h = j-quarter. w ring WRITE-ONCE (slot = timestep): no stale-L2 hazard.
//
// Barrier (contention-free): each block stores its iteration count to its OWN
// flag word (agent-scope store -> memory-side coherence point, no RMW, no
// buffer_wbl2). w data is written with agent-scope write-through 8B atomic
// stores; `s_waitcnt vmcnt(0)` before the flag store guarantees w is at L3
// before the flag becomes visible. Wave 0 polls all 128 flags of its chain
// with 2 coalesced loads + __all.
__global__ __launch_bounds__(256) void k_persist(
    const float* __restrict__ P, const float* __restrict__ q0vec,
    const float* __restrict__ iw, const float* __restrict__ colLSE,
    const int* __restrict__ sent, float* __restrict__ wring,
    float* __restrict__ dotpart, unsigned* __restrict__ flags) {
  const int c = blockIdx.x & 1;
  const int g = blockIdx.x >> 1;       // 0..127
  const int lane = threadIdx.x & 63;   // batch b
  const int h = __builtin_amdgcn_readfirstlane(threadIdx.x >> 6); // j-quarter
  const int i0 = g << 2;
  const int kmax = c ? 127 : 128;
  unsigned* const myflags = flags + (c << 7);

  // loop-invariant hoists
  const float4 cl = *(const float4*)(colLSE + i0);
  const float4* const P0 = (const float4*)(P + (size_t)(i0 + 0) * SS) + h * 32;
  const float4* const P1 = (const float4*)(P + (size_t)(i0 + 1) * SS) + h * 32;
  const float4* const P2 = (const float4*)(P + (size_t)(i0 + 2) * SS) + h * 32;
  const float4* const P3 = (const float4*)(P + (size_t)(i0 + 3) * SS) + h * 32;

  __shared__ float4 red[4][64];

  for (int k = 0; k <= kmax; ++k) {
    const int t0 = 2 * k;
    const int tw = t0 + c;
    const int td = tw - 1;
    const bool doW = (h == 0) && (tw <= 254);
    const bool doD = (h == 1) && (td >= 0);

    // Issue the scattered iw gathers BEFORE the barrier: their L2/L3 latency
    // hides under the flag spin.
    float4 ivW = make_float4(0.f, 0.f, 0.f, 0.f);
    float4 ivD = make_float4(0.f, 0.f, 0.f, 0.f);
    if (doW) {
      const int row = sent[lane * TT + tw];
      ivW = *(const float4*)(iw + (size_t)row * SS + i0);
    }
    if (doD) {
      const int row = sent[lane * TT + td];
      ivD = *(const float4*)(iw + (size_t)row * SS + i0);
    }

    if (k > 0) {
      __syncthreads();  // previous iteration's red reads complete
      if (h == 0) {
        const unsigned tgt = (unsigned)k;
        for (;;) {
          const unsigned va = __hip_atomic_load(myflags + lane, __ATOMIC_RELAXED,
                                                __HIP_MEMORY_SCOPE_AGENT);
          const unsigned vb = __hip_atomic_load(myflags + 64 + lane, __ATOMIC_RELAXED,
                                                __HIP_MEMORY_SCOPE_AGENT);
          if (__all((va >= tgt) && (vb >= tgt))) break;
          __builtin_amdgcn_s_sleep(2);
        }
      }
      __syncthreads();
    }

    float a0 = 0.f, a1 = 0.f, a2 = 0.f, a3 = 0.f;
    if (t0 == 0) {
      if (h == 0) {
        a0 = q0vec[i0 + 0]; a1 = q0vec[i0 + 1];
        a2 = q0vec[i0 + 2]; a3 = q0vec[i0 + 3];
      }
    } else {
      // Full-depth prefetch: all 32 w float4 loads in flight at once
      // (one L3 round-trip), then the FMA stream against L2-resident P.
      const float4* wv = (const float4*)(wring + (size_t)(tw - 2) * WSLOT)
                         + (size_t)h * 32 * 64;
      float4 wr[32];
      #pragma unroll
      for (int u = 0; u < 32; ++u) wr[u] = wv[u * 64 + lane];
      #pragma unroll
      for (int u = 0; u < 32; ++u) {
        const float4 p0 = P0[u];
        const float4 p1 = P1[u];
        const float4 p2 = P2[u];
        const float4 p3 = P3[u];
        a0 += wr[u].x * p0.x + wr[u].y * p0.y + wr[u].z * p0.z + wr[u].w * p0.w;
        a1 += wr[u].x * p1.x + wr[u].y * p1.y + wr[u].z * p1.z + wr[u].w * p1.w;
        a2 += wr[u].x * p2.x + wr[u].y * p2.y + wr[u].z * p2.z + wr[u].w * p2.w;
        a3 += wr[u].x * p3.x + wr[u].y * p3.y + wr[u].z * p3.z + wr[u].w * p3.w;
      }
    }

    red[h][lane] = make_float4(a0, a1, a2, a3);
    __syncthreads();

    if (h < 2) {
      const float4 r0 = red[0][lane], r1 = red[1][lane];
      const float4 r2 = red[2][lane], r3 = red[3][lane];
      const float s0 = (r0.x + r1.x) + (r2.x + r3.x);
      const float s1 = (r0.y + r1.y) + (r2.y + r3.y);
      const float s2 = (r0.z + r1.z) + (r2.z + r3.z);
      const float s3 = (r0.w + r1.w) + (r2.w + r3.w);

      if (doW) {
        float w0 = s0 * __expf(ivW.x - cl.x);
        float w1 = s1 * __expf(ivW.y - cl.y);
        float w2 = s2 * __expf(ivW.z - cl.z);
        float w3 = s3 * __expf(ivW.w - cl.w);
        float c0 = w0, c1 = w1, c2 = w2, c3 = w3;
        #pragma unroll
        for (int o = 32; o; o >>= 1) {
          c0 += __shfl_xor(c0, o);
          c1 += __shfl_xor(c1, o);
          c2 += __shfl_xor(c2, o);
          c3 += __shfl_xor(c3, o);
        }
        // write-through (agent) stores: data reaches L3 (coherence point)
        union { float2 f; unsigned long long u; } lo, hi;
        lo.f = make_float2(w0 / c0, w1 / c1);
        hi.f = make_float2(w2 / c2, w3 / c3);
        unsigned long long* wd = (unsigned long long*)
            ((float4*)(wring + (size_t)tw * WSLOT) + (g * 64 + lane));
        __hip_atomic_store(wd, lo.u, __ATOMIC_RELAXED, __HIP_MEMORY_SCOPE_AGENT);
        __hip_atomic_store(wd + 1, hi.u, __ATOMIC_RELAXED, __HIP_MEMORY_SCOPE_AGENT);
        asm volatile("s_waitcnt vmcnt(0)" ::: "memory");  // w acked at L3
        if (lane == 0)
          __hip_atomic_store(&myflags[g], (unsigned)(k + 1), __ATOMIC_RELAXED,
                             __HIP_MEMORY_SCOPE_AGENT);
      }

      if (doD) {
        const float dp = s0 * __expf(ivD.x - cl.x)
                       + s1 * __expf(ivD.y - cl.y)
                       + s2 * __expf(ivD.z - cl.z)
                       + s3 * __expf(ivD.w - cl.w);
        dotpart[((size_t)td * NS + g) * BB + lane] = dp;
      }
    }
  }
}

// ---------------- final reduction ----------------
__global__ void k_final(const float* __restrict__ dotpart, const float* __restrict__ masks,
                        float* __restrict__ out) {
  const int t = blockIdx.x;    // 256
  const int tid = threadIdx.x; // 256
  const int b = tid & 63, g = tid >> 6;
  float sum = 0.f;
  for (int s = g; s < NS; s += 4) sum += dotpart[((size_t)t * NS + s) * BB + b];
  __shared__ float red[4][64];
  red[g][b] = sum;
  __syncthreads();
  if (g == 0) {
    float tot = (red[0][b] + red[1][b]) + (red[2][b] + red[3][b]);
    float v = __logf(tot) * masks[b * TT + t];
    #pragma unroll
    for (int o = 32; o; o >>= 1) v += __shfl_xor(v, o);
    if (b == 0) atomicAdd(out, v);
  }
}

extern "C" void kernel_launch(void* const* d_in, const int* in_sizes, int n_in,
                              void* d_out, int out_size, void* d_ws, size_t ws_size,
                              hipStream_t stream) {
  const int* sent = (const int*)d_in[0];     // [64][256] int32
  const float* masks = (const float*)d_in[1];// [64][256]
  const float* iw = (const float*)d_in[2];   // [32000][512]
  const float* trans = (const float*)d_in[3];// [512][512]
  const float* begin = (const float*)d_in[4];// [512]
  float* out = (float*)d_out;
  float* ws = (float*)d_ws;

  // workspace carve (floats)
  float* P = ws;                            // 262144
  float* colLSE = P + 262144;               // 512
  float* psum = colLSE + 512;               // 256000
  float* colsum = psum + 256000;            // 512
  float* sb = colsum + 512;                 // 512
  float* q0vec = sb + 512;                  // 512
  float* dotpart = q0vec + 512;             // 256*128*64 = 2097152
  unsigned* flags = (unsigned*)(dotpart + 2097152); // 256 used, 512 reserved
  float* wring = (float*)flags + 512;       // 255 * 32768 = 8355840 (~33.4 MB)
  // total ~44 MB

  k_zero<<<1, 512, 0, stream>>>(out, colsum, flags);
  k_colpart<<<250, 256, 0, stream>>>(iw, psum);
  k_colreduce<<<25, 512, 0, stream>>>(psum, colsum);
  k_lse<<<1, 512, 0, stream>>>(colsum, colLSE);
  k_begin<<<1, 512, 0, stream>>>(begin, sb);
  k_transP<<<512, 64, 0, stream>>>(trans, sb, P, q0vec);

  {
    const float* Pp = P;
    const float* q0p = q0vec;
    const float* iwp = iw;
    const float* clp = colLSE;
    const int* sentp = sent;
    float* wrp = wring;
    float* dpp = dotpart;
    unsigned* fp = flags;
    void* args[] = {&Pp, &q0p, &iwp, &clp, &sentp, &wrp, &dpp, &fp};
    (void)hipLaunchCooperativeKernel((const void*)k_persist, dim3(256), dim3(256),
                                     args, 0, stream);
  }

  k_final<<<TT, 256, 0, stream>>>(dotpart, masks, out);
}